// Round 5
// baseline (399.750 us; speedup 1.0000x reference)
//
#include <hip/hip_runtime.h>

// GCN 2-layer, CSR aggregation, NO global atomics anywhere.
// N=50000 nodes, E=800000 edges, F=128, C=32.
// Pipeline: hist(partial LDS histograms) -> reduce(cnt_in,dinv) -> scan(row_ptr)
//           -> scan3(+per-slice offsets) -> fill2(LDS cursors) ->
//           GEMM1(+d_out) -> SpMM1(gather) -> GEMM2(relu/d_in/b1,+d_out) ->
//           SpMM2(gather, fused *d_in+b2)

#define F 128
#define C 32
#define PADN 50176       // 50000 padded to 49*1024
#define NR 49            // id ranges of 1024
#define NS 16            // edge slices
#define SCAN_BLOCKS 49   // PADN / 1024

// Partial histograms: block (r,s) counts ids in [r*1024,(r+1)*1024) over edge slice s.
__global__ __launch_bounds__(256) void hist_kernel(
    const int* __restrict__ src, const int* __restrict__ dst,
    int* __restrict__ partial_in, int* __restrict__ partial_out, int E) {
    __shared__ int h_in[1024];
    __shared__ int h_out[1024];
    const int tid = threadIdx.x;
    const int r = blockIdx.x % NR;
    const int s = blockIdx.x / NR;
#pragma unroll
    for (int j = 0; j < 4; ++j) { h_in[tid + j * 256] = 0; h_out[tid + j * 256] = 0; }
    __syncthreads();
    const int per = (E + NS - 1) / NS;
    const int lo = s * per;
    const int hi = min(E, lo + per);
    for (int e = lo + tid; e < hi; e += 256) {
        int d = dst[e];
        int v = src[e];
        if ((d >> 10) == r) atomicAdd(&h_in[d & 1023], 1);
        if ((v >> 10) == r) atomicAdd(&h_out[v & 1023], 1);
    }
    __syncthreads();
    int* pin  = partial_in  + s * PADN + r * 1024;
    int* pout = partial_out + s * PADN + r * 1024;
#pragma unroll
    for (int j = 0; j < 4; ++j) {
        int k = tid + j * 256;
        pin[k] = h_in[k];
        pout[k] = h_out[k];
    }
}

// cnt_in = sum_s partial_in; dinv_in/out fused.
__global__ void reduce_kernel(const int* __restrict__ partial_in, const int* __restrict__ partial_out,
                              int* __restrict__ cnt_in, float* __restrict__ dinv_in,
                              float* __restrict__ dinv_out, int n) {
    int i = blockIdx.x * blockDim.x + threadIdx.x;
    if (i >= n) return;
    int sin = 0, sout = 0;
#pragma unroll
    for (int s = 0; s < NS; ++s) {
        sin  += partial_in[s * PADN + i];
        sout += partial_out[s * PADN + i];
    }
    cnt_in[i] = sin;
    dinv_in[i]  = (sin  > 0) ? rsqrtf((float)sin)  : 1.0f;
    dinv_out[i] = (sout > 0) ? rsqrtf((float)sout) : 1.0f;
}

// exclusive scan stage 1: each block scans 1024 ints (256 thr x 4), writes block sum
__global__ __launch_bounds__(256) void scan1_kernel(const int* __restrict__ cnt,
                                                    int* __restrict__ part, int* __restrict__ bsum) {
    __shared__ int sdata[256];
    const int tid = threadIdx.x;
    const int base = blockIdx.x * 1024 + tid * 4;
    int4 c = *(const int4*)(cnt + base);
    int s = c.x + c.y + c.z + c.w;
    sdata[tid] = s;
    __syncthreads();
    for (int off = 1; off < 256; off <<= 1) {
        int v = 0;
        if (tid >= off) v = sdata[tid - off];
        __syncthreads();
        if (tid >= off) sdata[tid] += v;
        __syncthreads();
    }
    int excl = sdata[tid] - s;
    part[base]     = excl;
    part[base + 1] = excl + c.x;
    part[base + 2] = excl + c.x + c.y;
    part[base + 3] = excl + c.x + c.y + c.z;
    if (tid == 255) bsum[blockIdx.x] = sdata[255];
}

// stage 2: exclusive scan of block sums (nb <= 256), in place
__global__ __launch_bounds__(256) void scan2_kernel(int* __restrict__ bsum, int nb) {
    __shared__ int sdata[256];
    const int tid = threadIdx.x;
    int v = (tid < nb) ? bsum[tid] : 0;
    sdata[tid] = v;
    __syncthreads();
    for (int off = 1; off < 256; off <<= 1) {
        int t = 0;
        if (tid >= off) t = sdata[tid - off];
        __syncthreads();
        if (tid >= off) sdata[tid] += t;
        __syncthreads();
    }
    if (tid < nb) bsum[tid] = sdata[tid] - v;
}

// stage 3: finalize row_ptr; emit per-slice node offsets off[s][i]
__global__ void scan3_off_kernel(int* __restrict__ row_ptr, const int* __restrict__ bsum,
                                 const int* __restrict__ partial_in, int* __restrict__ off, int n) {
    int i = blockIdx.x * blockDim.x + threadIdx.x;
    if (i >= n) return;
    int rp = row_ptr[i] + bsum[i >> 10];
    row_ptr[i] = rp;
    int acc = rp;
#pragma unroll
    for (int s = 0; s < NS; ++s) {
        off[s * PADN + i] = acc;
        acc += partial_in[s * PADN + i];
    }
}

// CSR fill with LDS cursors only (no global atomics).
__global__ __launch_bounds__(256) void fill2_kernel(
    const int* __restrict__ src, const int* __restrict__ dst,
    const int* __restrict__ off, int* __restrict__ eidx, int E) {
    __shared__ int loff[1024];
    __shared__ int lcur[1024];
    const int tid = threadIdx.x;
    const int r = blockIdx.x % NR;
    const int s = blockIdx.x / NR;
#pragma unroll
    for (int j = 0; j < 4; ++j) {
        int k = tid + j * 256;
        loff[k] = off[s * PADN + r * 1024 + k];
        lcur[k] = 0;
    }
    __syncthreads();
    const int per = (E + NS - 1) / NS;
    const int lo = s * per;
    const int hi = min(E, lo + per);
    for (int e = lo + tid; e < hi; e += 256) {
        int d = dst[e];
        if ((d >> 10) == r) {
            int v = src[e];
            int k = d & 1023;
            int pos = loff[k] + atomicAdd(&lcur[k], 1);
            eidx[pos] = v;
        }
    }
}

// H1[n][m] = (sum_k X[n][k] W1[k][m]) * dinv_out[n]
__global__ __launch_bounds__(256) void gemm1_kernel(
    const float* __restrict__ X, const float* __restrict__ W,
    const float* __restrict__ dinv_out, float* __restrict__ H1, int N) {
    __shared__ float ws[32 * 128];
    __shared__ float xs[32 * 36];
    const int tid = threadIdx.x;
    const int m0 = tid & 15;
    const int rr = tid >> 4;
    const int rbase = blockIdx.x * 32;

    float4 a00 = {0,0,0,0}, a01 = {0,0,0,0}, a10 = {0,0,0,0}, a11 = {0,0,0,0};

    for (int kt = 0; kt < 4; ++kt) {
        const float4* W4 = (const float4*)(W + kt * 32 * 128);
        float4* ws4 = (float4*)ws;
#pragma unroll
        for (int j = 0; j < 4; ++j) ws4[tid + j * 256] = W4[tid + j * 256];
        {
            int r = tid >> 3, k4 = tid & 7;
            int row = rbase + r;
            float4 v = make_float4(0.f, 0.f, 0.f, 0.f);
            if (row < N) v = *(const float4*)(X + (size_t)row * F + kt * 32 + k4 * 4);
            int base = r * 36 + k4 * 4;
            xs[base] = v.x; xs[base + 1] = v.y; xs[base + 2] = v.z; xs[base + 3] = v.w;
        }
        __syncthreads();
#pragma unroll
        for (int kk = 0; kk < 32; ++kk) {
            float xa = xs[(rr * 2) * 36 + kk];
            float xb = xs[(rr * 2 + 1) * 36 + kk];
            float4 wA = *(const float4*)(ws + kk * 128 + m0 * 4);
            float4 wB = *(const float4*)(ws + kk * 128 + 64 + m0 * 4);
            a00.x += xa * wA.x; a00.y += xa * wA.y; a00.z += xa * wA.z; a00.w += xa * wA.w;
            a01.x += xa * wB.x; a01.y += xa * wB.y; a01.z += xa * wB.z; a01.w += xa * wB.w;
            a10.x += xb * wA.x; a10.y += xb * wA.y; a10.z += xb * wA.z; a10.w += xb * wA.w;
            a11.x += xb * wB.x; a11.y += xb * wB.y; a11.z += xb * wB.z; a11.w += xb * wB.w;
        }
        __syncthreads();
    }
    int row0 = rbase + rr * 2;
    int row1 = row0 + 1;
    if (row0 < N) {
        float s = dinv_out[row0];
        float4 o0 = {a00.x * s, a00.y * s, a00.z * s, a00.w * s};
        float4 o1 = {a01.x * s, a01.y * s, a01.z * s, a01.w * s};
        *(float4*)(H1 + (size_t)row0 * F + m0 * 4) = o0;
        *(float4*)(H1 + (size_t)row0 * F + 64 + m0 * 4) = o1;
    }
    if (row1 < N) {
        float s = dinv_out[row1];
        float4 o0 = {a10.x * s, a10.y * s, a10.z * s, a10.w * s};
        float4 o1 = {a11.x * s, a11.y * s, a11.z * s, a11.w * s};
        *(float4*)(H1 + (size_t)row1 * F + m0 * 4) = o0;
        *(float4*)(H1 + (size_t)row1 * F + 64 + m0 * 4) = o1;
    }
}

// AGG1[n][:] = sum_{e in CSR row n} H1[eidx[e]][:]
// one wave per node, lane = 2 floats; eidx loads wave-uniform (no shfl)
__global__ __launch_bounds__(256) void spmm_csr1_kernel(
    const float* __restrict__ H1, const int* __restrict__ row_ptr,
    const int* __restrict__ cnt, const int* __restrict__ eidx,
    float* __restrict__ AGG1, int N) {
    int node = blockIdx.x * 4 + (threadIdx.x >> 6);
    if (node >= N) return;
    const int l = threadIdx.x & 63;
    const int start = row_ptr[node];
    const int deg = cnt[node];
    const float* Hb = H1 + l * 2;
    float2 a0 = {0.f,0.f}, a1 = {0.f,0.f}, a2 = {0.f,0.f}, a3 = {0.f,0.f};
    int i = 0;
    for (; i + 3 < deg; i += 4) {
        int s0 = eidx[start + i];
        int s1 = eidx[start + i + 1];
        int s2 = eidx[start + i + 2];
        int s3 = eidx[start + i + 3];
        float2 v0 = *(const float2*)(Hb + (size_t)s0 * F);
        float2 v1 = *(const float2*)(Hb + (size_t)s1 * F);
        float2 v2 = *(const float2*)(Hb + (size_t)s2 * F);
        float2 v3 = *(const float2*)(Hb + (size_t)s3 * F);
        a0.x += v0.x; a0.y += v0.y;
        a1.x += v1.x; a1.y += v1.y;
        a2.x += v2.x; a2.y += v2.y;
        a3.x += v3.x; a3.y += v3.y;
    }
    for (; i < deg; ++i) {
        int s0 = eidx[start + i];
        float2 v0 = *(const float2*)(Hb + (size_t)s0 * F);
        a0.x += v0.x; a0.y += v0.y;
    }
    float2 o = {a0.x + a1.x + a2.x + a3.x, a0.y + a1.y + a2.y + a3.y};
    *(float2*)(AGG1 + (size_t)node * F + l * 2) = o;
}

// H2[n][m] = (sum_k relu(AGG1[n][k]*dinv_in[n] + b1[k]) * W2[k][m]) * dinv_out[n]
__global__ __launch_bounds__(256) void gemm2_kernel(
    const float* __restrict__ AGG1, const float* __restrict__ b1,
    const float* __restrict__ dinv_in, const float* __restrict__ W2,
    const float* __restrict__ dinv_out, float* __restrict__ H2, int N) {
    __shared__ float ws[F * C];
    __shared__ float xs[64 * 132];
    const int tid = threadIdx.x;
    const int rbase = blockIdx.x * 64;
    {
        float4* ws4 = (float4*)ws;
        const float4* W4 = (const float4*)W2;
#pragma unroll
        for (int j = 0; j < 4; ++j) ws4[tid + j * 256] = W4[tid + j * 256];
    }
#pragma unroll
    for (int j = 0; j < 8; ++j) {
        int i4 = tid + j * 256;
        int r = i4 >> 5, k4 = i4 & 31;
        int row = rbase + r;
        float4 v = make_float4(0.f, 0.f, 0.f, 0.f);
        float di = 0.f;
        if (row < N) {
            v = *(const float4*)(AGG1 + (size_t)row * F + k4 * 4);
            di = dinv_in[row];
        }
        float4 bb = *(const float4*)(b1 + k4 * 4);
        int base = r * 132 + k4 * 4;
        xs[base]     = fmaxf(fmaf(v.x, di, bb.x), 0.f);
        xs[base + 1] = fmaxf(fmaf(v.y, di, bb.y), 0.f);
        xs[base + 2] = fmaxf(fmaf(v.z, di, bb.z), 0.f);
        xs[base + 3] = fmaxf(fmaf(v.w, di, bb.w), 0.f);
    }
    __syncthreads();
    const int m0 = tid & 7;
    const int rr = tid >> 3;
    float4 a0 = {0,0,0,0}, a1 = {0,0,0,0};
#pragma unroll 8
    for (int k = 0; k < F; ++k) {
        float4 w = *(const float4*)(ws + k * C + m0 * 4);
        float xa = xs[(rr * 2) * 132 + k];
        float xb = xs[(rr * 2 + 1) * 132 + k];
        a0.x += xa * w.x; a0.y += xa * w.y; a0.z += xa * w.z; a0.w += xa * w.w;
        a1.x += xb * w.x; a1.y += xb * w.y; a1.z += xb * w.z; a1.w += xb * w.w;
    }
    int row0 = rbase + rr * 2;
    int row1 = row0 + 1;
    if (row0 < N) {
        float s = dinv_out[row0];
        float4 o = {a0.x * s, a0.y * s, a0.z * s, a0.w * s};
        *(float4*)(H2 + (size_t)row0 * C + m0 * 4) = o;
    }
    if (row1 < N) {
        float s = dinv_out[row1];
        float4 o = {a1.x * s, a1.y * s, a1.z * s, a1.w * s};
        *(float4*)(H2 + (size_t)row1 * C + m0 * 4) = o;
    }
}

// out[n][:] = (sum_{e in row n} H2[eidx[e]][:]) * dinv_in[n] + b2
// HALF-wave (32 lanes) per node, lane = col
__global__ __launch_bounds__(256) void spmm_csr2_kernel(
    const float* __restrict__ H2, const int* __restrict__ row_ptr,
    const int* __restrict__ cnt, const int* __restrict__ eidx,
    const float* __restrict__ dinv_in, const float* __restrict__ b2,
    float* __restrict__ out, int N) {
    int node = blockIdx.x * 8 + (threadIdx.x >> 5);
    if (node >= N) return;
    const int col = threadIdx.x & 31;
    const int start = row_ptr[node];
    const int deg = cnt[node];
    float acc0 = 0.f, acc1 = 0.f;
    int i = 0;
    for (; i + 1 < deg; i += 2) {
        int s0 = eidx[start + i];
        int s1 = eidx[start + i + 1];
        acc0 += H2[(size_t)s0 * C + col];
        acc1 += H2[(size_t)s1 * C + col];
    }
    if (i < deg) acc0 += H2[(size_t)eidx[start + i] * C + col];
    out[(size_t)node * C + col] = fmaf(acc0 + acc1, dinv_in[node], b2[col]);
}

extern "C" void kernel_launch(void* const* d_in, const int* in_sizes, int n_in,
                              void* d_out, int out_size, void* d_ws, size_t ws_size,
                              hipStream_t stream) {
    const float* X  = (const float*)d_in[0];
    // d_in[1] = edge_encodings: unused by the reference
    const float* W1 = (const float*)d_in[2];
    const float* b1 = (const float*)d_in[3];
    const float* W2 = (const float*)d_in[4];
    const float* b2 = (const float*)d_in[5];
    const int*   ei = (const int*)d_in[6];

    const int N = in_sizes[0] / F;   // 50000
    const int E = in_sizes[6] / 2;   // 800000
    const int* src = ei;
    const int* dst = ei + E;

    // Workspace layout (elements, 4B each). Total ~55.2 MB.
    float* wsf      = (float*)d_ws;
    float* dinv_out = wsf;                         // PADN
    float* dinv_in  = wsf + PADN;                  // PADN
    int* cnt_in  = (int*)(wsf + 2 * PADN);         // PADN
    int* row_ptr = cnt_in + PADN;                  // PADN
    int* bsum    = row_ptr + PADN;                 // 256
    int* eidx    = bsum + 256;                     // E
    float* H1    = (float*)(eidx + E);             // N*F
    int* partial_in  = (int*)(H1 + (size_t)N * F); // NS*PADN
    int* partial_out = partial_in + NS * PADN;     // NS*PADN
    int* off         = partial_out;                // alias: partial_out dead after reduce
    float* AGG1  = (float*)partial_in;             // alias: partials/off dead after fill2
    float* H2    = H1;                             // alias: H1 dead after spmm_csr1
    float* outp  = (float*)d_out;                  // N*C

    hist_kernel<<<NR * NS, 256, 0, stream>>>(src, dst, partial_in, partial_out, E);
    reduce_kernel<<<PADN / 256, 256, 0, stream>>>(partial_in, partial_out, cnt_in, dinv_in, dinv_out, PADN);
    scan1_kernel<<<SCAN_BLOCKS, 256, 0, stream>>>(cnt_in, row_ptr, bsum);
    scan2_kernel<<<1, 256, 0, stream>>>(bsum, SCAN_BLOCKS);
    scan3_off_kernel<<<PADN / 256, 256, 0, stream>>>(row_ptr, bsum, partial_in, off, PADN);
    fill2_kernel<<<NR * NS, 256, 0, stream>>>(src, dst, off, eidx, E);

    gemm1_kernel<<<(N + 31) / 32, 256, 0, stream>>>(X, W1, dinv_out, H1, N);
    spmm_csr1_kernel<<<(N + 3) / 4, 256, 0, stream>>>(H1, row_ptr, cnt_in, eidx, AGG1, N);
    gemm2_kernel<<<(N + 63) / 64, 256, 0, stream>>>(AGG1, b1, dinv_in, W2, dinv_out, H2, N);
    spmm_csr2_kernel<<<(N + 7) / 8, 256, 0, stream>>>(H2, row_ptr, cnt_in, eidx, dinv_in, b2, outp, N);
}

// Round 6
// 337.062 us; speedup vs baseline: 1.1860x; 1.1860x over previous
//
#include <hip/hip_runtime.h>

// GCN 2-layer, CSR aggregation (atomic CSR build, reverted from r5 hist scheme).
// H1 stored as bf16 to halve SpMM1 gather traffic; all accumulation fp32.
// N=50000 nodes, E=800000 edges, F=128, C=32.

#define F 128
#define C 32
#define PADN 50176       // 50000 padded to 49*1024
#define SCAN_BLOCKS 49   // PADN / 1024

static __device__ __forceinline__ unsigned short bf16_bits(float f) {
    union { float f; unsigned int u; } v; v.f = f;
    unsigned int r = v.u + 0x7fffu + ((v.u >> 16) & 1u);   // round-to-nearest-even
    return (unsigned short)(r >> 16);
}

__global__ void deg_cnt_kernel(const int* __restrict__ src, const int* __restrict__ dst,
                               int* __restrict__ cnt_out, int* __restrict__ cnt_in, int E) {
    int i = blockIdx.x * blockDim.x + threadIdx.x;
    if (i >= E) return;
    atomicAdd(&cnt_out[src[i]], 1);
    atomicAdd(&cnt_in[dst[i]], 1);
}

__global__ void dinv_kernel(const int* __restrict__ cnt_out, const int* __restrict__ cnt_in,
                            float* __restrict__ dinv_out, float* __restrict__ dinv_in, int n) {
    int i = blockIdx.x * blockDim.x + threadIdx.x;
    if (i >= n) return;
    int co = cnt_out[i], ci = cnt_in[i];
    dinv_out[i] = (co > 0) ? rsqrtf((float)co) : 1.0f;
    dinv_in[i]  = (ci > 0) ? rsqrtf((float)ci) : 1.0f;
}

// exclusive scan stage 1: each block scans 1024 ints (256 thr x 4), writes block sum
__global__ __launch_bounds__(256) void scan1_kernel(const int* __restrict__ cnt,
                                                    int* __restrict__ part, int* __restrict__ bsum) {
    __shared__ int sdata[256];
    const int tid = threadIdx.x;
    const int base = blockIdx.x * 1024 + tid * 4;
    int4 c = *(const int4*)(cnt + base);
    int s = c.x + c.y + c.z + c.w;
    sdata[tid] = s;
    __syncthreads();
    for (int off = 1; off < 256; off <<= 1) {
        int v = 0;
        if (tid >= off) v = sdata[tid - off];
        __syncthreads();
        if (tid >= off) sdata[tid] += v;
        __syncthreads();
    }
    int excl = sdata[tid] - s;
    part[base]     = excl;
    part[base + 1] = excl + c.x;
    part[base + 2] = excl + c.x + c.y;
    part[base + 3] = excl + c.x + c.y + c.z;
    if (tid == 255) bsum[blockIdx.x] = sdata[255];
}

// stage 2: exclusive scan of block sums (nb <= 256), in place
__global__ __launch_bounds__(256) void scan2_kernel(int* __restrict__ bsum, int nb) {
    __shared__ int sdata[256];
    const int tid = threadIdx.x;
    int v = (tid < nb) ? bsum[tid] : 0;
    sdata[tid] = v;
    __syncthreads();
    for (int off = 1; off < 256; off <<= 1) {
        int t = 0;
        if (tid >= off) t = sdata[tid - off];
        __syncthreads();
        if (tid >= off) sdata[tid] += t;
        __syncthreads();
    }
    if (tid < nb) bsum[tid] = sdata[tid] - v;
}

// stage 3: add block offsets; duplicate into cursor for the fill pass
__global__ void scan3_kernel(int* __restrict__ row_ptr, int* __restrict__ cursor,
                             const int* __restrict__ bsum, int n) {
    int i = blockIdx.x * blockDim.x + threadIdx.x;
    if (i >= n) return;
    int v = row_ptr[i] + bsum[i >> 10];
    row_ptr[i] = v;
    cursor[i] = v;
}

__global__ void fill_kernel(const int* __restrict__ src, const int* __restrict__ dst,
                            int* __restrict__ cursor, int* __restrict__ eidx, int E) {
    int e = blockIdx.x * blockDim.x + threadIdx.x;
    if (e >= E) return;
    int d = dst[e];
    int pos = atomicAdd(&cursor[d], 1);
    eidx[pos] = src[e];
}

// H1[n][m] = bf16( (sum_k X[n][k] W1[k][m]) * dinv_out[n] )
__global__ __launch_bounds__(256) void gemm1_kernel(
    const float* __restrict__ X, const float* __restrict__ W,
    const float* __restrict__ dinv_out, unsigned short* __restrict__ H1, int N) {
    __shared__ float ws[32 * 128];
    __shared__ float xs[32 * 36];
    const int tid = threadIdx.x;
    const int m0 = tid & 15;
    const int rr = tid >> 4;
    const int rbase = blockIdx.x * 32;

    float4 a00 = {0,0,0,0}, a01 = {0,0,0,0}, a10 = {0,0,0,0}, a11 = {0,0,0,0};

    for (int kt = 0; kt < 4; ++kt) {
        const float4* W4 = (const float4*)(W + kt * 32 * 128);
        float4* ws4 = (float4*)ws;
#pragma unroll
        for (int j = 0; j < 4; ++j) ws4[tid + j * 256] = W4[tid + j * 256];
        {
            int r = tid >> 3, k4 = tid & 7;
            int row = rbase + r;
            float4 v = make_float4(0.f, 0.f, 0.f, 0.f);
            if (row < N) v = *(const float4*)(X + (size_t)row * F + kt * 32 + k4 * 4);
            int base = r * 36 + k4 * 4;
            xs[base] = v.x; xs[base + 1] = v.y; xs[base + 2] = v.z; xs[base + 3] = v.w;
        }
        __syncthreads();
#pragma unroll
        for (int kk = 0; kk < 32; ++kk) {
            float xa = xs[(rr * 2) * 36 + kk];
            float xb = xs[(rr * 2 + 1) * 36 + kk];
            float4 wA = *(const float4*)(ws + kk * 128 + m0 * 4);
            float4 wB = *(const float4*)(ws + kk * 128 + 64 + m0 * 4);
            a00.x += xa * wA.x; a00.y += xa * wA.y; a00.z += xa * wA.z; a00.w += xa * wA.w;
            a01.x += xa * wB.x; a01.y += xa * wB.y; a01.z += xa * wB.z; a01.w += xa * wB.w;
            a10.x += xb * wA.x; a10.y += xb * wA.y; a10.z += xb * wA.z; a10.w += xb * wA.w;
            a11.x += xb * wB.x; a11.y += xb * wB.y; a11.z += xb * wB.z; a11.w += xb * wB.w;
        }
        __syncthreads();
    }
    int row0 = rbase + rr * 2;
    int row1 = row0 + 1;
    if (row0 < N) {
        float s = dinv_out[row0];
        ushort4 p0, p1;
        p0.x = bf16_bits(a00.x * s); p0.y = bf16_bits(a00.y * s);
        p0.z = bf16_bits(a00.z * s); p0.w = bf16_bits(a00.w * s);
        p1.x = bf16_bits(a01.x * s); p1.y = bf16_bits(a01.y * s);
        p1.z = bf16_bits(a01.z * s); p1.w = bf16_bits(a01.w * s);
        *(ushort4*)(H1 + (size_t)row0 * F + m0 * 4) = p0;
        *(ushort4*)(H1 + (size_t)row0 * F + 64 + m0 * 4) = p1;
    }
    if (row1 < N) {
        float s = dinv_out[row1];
        ushort4 p0, p1;
        p0.x = bf16_bits(a10.x * s); p0.y = bf16_bits(a10.y * s);
        p0.z = bf16_bits(a10.z * s); p0.w = bf16_bits(a10.w * s);
        p1.x = bf16_bits(a11.x * s); p1.y = bf16_bits(a11.y * s);
        p1.z = bf16_bits(a11.z * s); p1.w = bf16_bits(a11.w * s);
        *(ushort4*)(H1 + (size_t)row1 * F + m0 * 4) = p0;
        *(ushort4*)(H1 + (size_t)row1 * F + 64 + m0 * 4) = p1;
    }
}

// AGG1[n][:] = sum_{e in CSR row n} H1[eidx[e]][:]  (H1 bf16, fp32 accumulate)
// one wave per node, lane = 2 feats (one u32 = 2 bf16); eidx loads wave-uniform
__global__ __launch_bounds__(256) void spmm_csr1_kernel(
    const unsigned short* __restrict__ H1, const int* __restrict__ row_ptr,
    const int* __restrict__ cnt, const int* __restrict__ eidx,
    float* __restrict__ AGG1, int N) {
    int node = blockIdx.x * 4 + (threadIdx.x >> 6);
    if (node >= N) return;
    const int l = threadIdx.x & 63;
    const int start = row_ptr[node];
    const int deg = cnt[node];
    const unsigned int* Hb = (const unsigned int*)H1 + l;   // + s*64 per row
    float2 a0 = {0.f,0.f}, a1 = {0.f,0.f}, a2 = {0.f,0.f}, a3 = {0.f,0.f};
    int i = 0;
    for (; i + 3 < deg; i += 4) {
        int s0 = eidx[start + i];
        int s1 = eidx[start + i + 1];
        int s2 = eidx[start + i + 2];
        int s3 = eidx[start + i + 3];
        unsigned int w0 = Hb[(size_t)s0 * 64];
        unsigned int w1 = Hb[(size_t)s1 * 64];
        unsigned int w2 = Hb[(size_t)s2 * 64];
        unsigned int w3 = Hb[(size_t)s3 * 64];
        a0.x += __uint_as_float(w0 << 16); a0.y += __uint_as_float(w0 & 0xffff0000u);
        a1.x += __uint_as_float(w1 << 16); a1.y += __uint_as_float(w1 & 0xffff0000u);
        a2.x += __uint_as_float(w2 << 16); a2.y += __uint_as_float(w2 & 0xffff0000u);
        a3.x += __uint_as_float(w3 << 16); a3.y += __uint_as_float(w3 & 0xffff0000u);
    }
    for (; i < deg; ++i) {
        int s0 = eidx[start + i];
        unsigned int w0 = Hb[(size_t)s0 * 64];
        a0.x += __uint_as_float(w0 << 16); a0.y += __uint_as_float(w0 & 0xffff0000u);
    }
    float2 o = {a0.x + a1.x + a2.x + a3.x, a0.y + a1.y + a2.y + a3.y};
    *(float2*)(AGG1 + (size_t)node * F + l * 2) = o;
}

// H2[n][m] = (sum_k relu(AGG1[n][k]*dinv_in[n] + b1[k]) * W2[k][m]) * dinv_out[n]
__global__ __launch_bounds__(256) void gemm2_kernel(
    const float* __restrict__ AGG1, const float* __restrict__ b1,
    const float* __restrict__ dinv_in, const float* __restrict__ W2,
    const float* __restrict__ dinv_out, float* __restrict__ H2, int N) {
    __shared__ float ws[F * C];
    __shared__ float xs[64 * 132];
    const int tid = threadIdx.x;
    const int rbase = blockIdx.x * 64;
    {
        float4* ws4 = (float4*)ws;
        const float4* W4 = (const float4*)W2;
#pragma unroll
        for (int j = 0; j < 4; ++j) ws4[tid + j * 256] = W4[tid + j * 256];
    }
#pragma unroll
    for (int j = 0; j < 8; ++j) {
        int i4 = tid + j * 256;
        int r = i4 >> 5, k4 = i4 & 31;
        int row = rbase + r;
        float4 v = make_float4(0.f, 0.f, 0.f, 0.f);
        float di = 0.f;
        if (row < N) {
            v = *(const float4*)(AGG1 + (size_t)row * F + k4 * 4);
            di = dinv_in[row];
        }
        float4 bb = *(const float4*)(b1 + k4 * 4);
        int base = r * 132 + k4 * 4;
        xs[base]     = fmaxf(fmaf(v.x, di, bb.x), 0.f);
        xs[base + 1] = fmaxf(fmaf(v.y, di, bb.y), 0.f);
        xs[base + 2] = fmaxf(fmaf(v.z, di, bb.z), 0.f);
        xs[base + 3] = fmaxf(fmaf(v.w, di, bb.w), 0.f);
    }
    __syncthreads();
    const int m0 = tid & 7;
    const int rr = tid >> 3;
    float4 a0 = {0,0,0,0}, a1 = {0,0,0,0};
#pragma unroll 8
    for (int k = 0; k < F; ++k) {
        float4 w = *(const float4*)(ws + k * C + m0 * 4);
        float xa = xs[(rr * 2) * 132 + k];
        float xb = xs[(rr * 2 + 1) * 132 + k];
        a0.x += xa * w.x; a0.y += xa * w.y; a0.z += xa * w.z; a0.w += xa * w.w;
        a1.x += xb * w.x; a1.y += xb * w.y; a1.z += xb * w.z; a1.w += xb * w.w;
    }
    int row0 = rbase + rr * 2;
    int row1 = row0 + 1;
    if (row0 < N) {
        float s = dinv_out[row0];
        float4 o = {a0.x * s, a0.y * s, a0.z * s, a0.w * s};
        *(float4*)(H2 + (size_t)row0 * C + m0 * 4) = o;
    }
    if (row1 < N) {
        float s = dinv_out[row1];
        float4 o = {a1.x * s, a1.y * s, a1.z * s, a1.w * s};
        *(float4*)(H2 + (size_t)row1 * C + m0 * 4) = o;
    }
}

// out[n][:] = (sum_{e in row n} H2[eidx[e]][:]) * dinv_in[n] + b2
// HALF-wave (32 lanes) per node, lane = col
__global__ __launch_bounds__(256) void spmm_csr2_kernel(
    const float* __restrict__ H2, const int* __restrict__ row_ptr,
    const int* __restrict__ cnt, const int* __restrict__ eidx,
    const float* __restrict__ dinv_in, const float* __restrict__ b2,
    float* __restrict__ out, int N) {
    int node = blockIdx.x * 8 + (threadIdx.x >> 5);
    if (node >= N) return;
    const int col = threadIdx.x & 31;
    const int start = row_ptr[node];
    const int deg = cnt[node];
    float acc0 = 0.f, acc1 = 0.f;
    int i = 0;
    for (; i + 1 < deg; i += 2) {
        int s0 = eidx[start + i];
        int s1 = eidx[start + i + 1];
        acc0 += H2[(size_t)s0 * C + col];
        acc1 += H2[(size_t)s1 * C + col];
    }
    if (i < deg) acc0 += H2[(size_t)eidx[start + i] * C + col];
    out[(size_t)node * C + col] = fmaf(acc0 + acc1, dinv_in[node], b2[col]);
}

extern "C" void kernel_launch(void* const* d_in, const int* in_sizes, int n_in,
                              void* d_out, int out_size, void* d_ws, size_t ws_size,
                              hipStream_t stream) {
    const float* X  = (const float*)d_in[0];
    // d_in[1] = edge_encodings: unused by the reference
    const float* W1 = (const float*)d_in[2];
    const float* b1 = (const float*)d_in[3];
    const float* W2 = (const float*)d_in[4];
    const float* b2 = (const float*)d_in[5];
    const int*   ei = (const int*)d_in[6];

    const int N = in_sizes[0] / F;   // 50000
    const int E = in_sizes[6] / 2;   // 800000
    const int* src = ei;
    const int* dst = ei + E;

    float* wsf      = (float*)d_ws;
    float* dinv_out = wsf;                     // PADN
    float* dinv_in  = wsf + PADN;              // PADN
    int* cnt_out = (int*)(wsf + 2 * PADN);     // PADN
    int* cnt_in  = cnt_out + PADN;             // PADN
    int* row_ptr = cnt_in + PADN;              // PADN
    int* cursor  = row_ptr + PADN;             // PADN
    int* bsum    = cursor + PADN;              // 256
    int* eidx    = bsum + 256;                 // E
    unsigned short* H1 = (unsigned short*)(eidx + E);  // N*F bf16 (16B-aligned)
    float* AGG1  = (float*)(H1 + (size_t)N * F);       // N*F fp32 (16B-aligned)
    float* H2    = (float*)H1;                 // alias: H1 dead after spmm_csr1; N*C fp32 fits
    float* outp  = (float*)d_out;              // N*C

    hipMemsetAsync(cnt_out, 0, (size_t)2 * PADN * sizeof(int), stream);

    deg_cnt_kernel<<<(E + 255) / 256, 256, 0, stream>>>(src, dst, cnt_out, cnt_in, E);
    dinv_kernel<<<PADN / 256, 256, 0, stream>>>(cnt_out, cnt_in, dinv_out, dinv_in, PADN);
    scan1_kernel<<<SCAN_BLOCKS, 256, 0, stream>>>(cnt_in, row_ptr, bsum);
    scan2_kernel<<<1, 256, 0, stream>>>(bsum, SCAN_BLOCKS);
    scan3_kernel<<<PADN / 256, 256, 0, stream>>>(row_ptr, cursor, bsum, PADN);
    fill_kernel<<<(E + 255) / 256, 256, 0, stream>>>(src, dst, cursor, eidx, E);

    gemm1_kernel<<<(N + 31) / 32, 256, 0, stream>>>(X, W1, dinv_out, H1, N);
    spmm_csr1_kernel<<<(N + 3) / 4, 256, 0, stream>>>(H1, row_ptr, cnt_in, eidx, AGG1, N);
    gemm2_kernel<<<(N + 63) / 64, 256, 0, stream>>>(AGG1, b1, dinv_in, W2, dinv_out, H2, N);
    spmm_csr2_kernel<<<(N + 7) / 8, 256, 0, stream>>>(H2, row_ptr, cnt_in, eidx, dinv_in, b2, outp, N);
}

// Round 7
// 287.618 us; speedup vs baseline: 1.3899x; 1.1719x over previous
//
#include <hip/hip_runtime.h>

// GCN 2-layer, CSR aggregation. H1 bf16, fp32 accumulate.
// CSR build: passA (dst atomic count -> also edge position), hist_out (LDS u8
// histogram, no global atomics), scan, fillB (atomic-free scatter).
// N=50000 nodes, E=800000 edges, F=128, C=32.

#define F 128
#define C 32
#define PADN 50176       // 50000 padded to 49*1024
#define SCAN_BLOCKS 49   // PADN / 1024
#define HB 256           // histogram blocks
#define PADN4 (PADN / 4) // u32 groups of 4 packed u8 counters

static __device__ __forceinline__ unsigned short bf16_bits(float f) {
    union { float f; unsigned int u; } v; v.f = f;
    unsigned int r = v.u + 0x7fffu + ((v.u >> 16) & 1u);   // round-to-nearest-even
    return (unsigned short)(r >> 16);
}

// In-degree count; atomic return value doubles as the edge's slot in its CSR row.
__global__ void passA_kernel(const int* __restrict__ dst, int* __restrict__ cnt_in,
                             unsigned short* __restrict__ pos, int E) {
    int e = blockIdx.x * blockDim.x + threadIdx.x;
    if (e >= E) return;
    int p = atomicAdd(&cnt_in[dst[e]], 1);
    pos[e] = (unsigned short)p;
}

// Out-degree partial histograms: block b histograms its edge slice over ALL nodes
// into packed-u8 LDS counters (no global atomics, each edge read once).
__global__ __launch_bounds__(256) void hist_out_kernel(
    const int* __restrict__ src, unsigned int* __restrict__ partial, int E) {
    __shared__ unsigned int h[PADN4];   // 50176 u8 counters, 50.2 KB
    const int tid = threadIdx.x;
    for (int j = tid; j < PADN4; j += 256) h[j] = 0u;
    __syncthreads();
    const int per = (E + HB - 1) / HB;
    const int lo = blockIdx.x * per;
    const int hi = min(E, lo + per);
    for (int e = lo + tid; e < hi; e += 256) {
        int v = src[e];
        atomicAdd(&h[v >> 2], 1u << ((v & 3) * 8));
    }
    __syncthreads();
    unsigned int* p = partial + (size_t)blockIdx.x * PADN4;
    for (int j = tid; j < PADN4; j += 256) p[j] = h[j];
}

// Sum u8 partials -> out-degree; fused dinv_out / dinv_in.
__global__ void reduce_dinv_kernel(const unsigned int* __restrict__ partial,
                                   const int* __restrict__ cnt_in,
                                   float* __restrict__ dinv_out, float* __restrict__ dinv_in,
                                   int n4) {
    int i = blockIdx.x * blockDim.x + threadIdx.x;
    if (i >= n4) return;
    unsigned int s0 = 0, s1 = 0, s2 = 0, s3 = 0;
#pragma unroll 8
    for (int b = 0; b < HB; ++b) {
        unsigned int w = partial[(size_t)b * PADN4 + i];
        s0 += w & 0xffu; s1 += (w >> 8) & 0xffu; s2 += (w >> 16) & 0xffu; s3 += w >> 24;
    }
    int base = i * 4;
    dinv_out[base + 0] = s0 ? rsqrtf((float)s0) : 1.0f;
    dinv_out[base + 1] = s1 ? rsqrtf((float)s1) : 1.0f;
    dinv_out[base + 2] = s2 ? rsqrtf((float)s2) : 1.0f;
    dinv_out[base + 3] = s3 ? rsqrtf((float)s3) : 1.0f;
    int4 c = *(const int4*)(cnt_in + base);
    dinv_in[base + 0] = c.x > 0 ? rsqrtf((float)c.x) : 1.0f;
    dinv_in[base + 1] = c.y > 0 ? rsqrtf((float)c.y) : 1.0f;
    dinv_in[base + 2] = c.z > 0 ? rsqrtf((float)c.z) : 1.0f;
    dinv_in[base + 3] = c.w > 0 ? rsqrtf((float)c.w) : 1.0f;
}

// exclusive scan stage 1: each block scans 1024 ints (256 thr x 4), writes block sum
__global__ __launch_bounds__(256) void scan1_kernel(const int* __restrict__ cnt,
                                                    int* __restrict__ part, int* __restrict__ bsum) {
    __shared__ int sdata[256];
    const int tid = threadIdx.x;
    const int base = blockIdx.x * 1024 + tid * 4;
    int4 c = *(const int4*)(cnt + base);
    int s = c.x + c.y + c.z + c.w;
    sdata[tid] = s;
    __syncthreads();
    for (int off = 1; off < 256; off <<= 1) {
        int v = 0;
        if (tid >= off) v = sdata[tid - off];
        __syncthreads();
        if (tid >= off) sdata[tid] += v;
        __syncthreads();
    }
    int excl = sdata[tid] - s;
    part[base]     = excl;
    part[base + 1] = excl + c.x;
    part[base + 2] = excl + c.x + c.y;
    part[base + 3] = excl + c.x + c.y + c.z;
    if (tid == 255) bsum[blockIdx.x] = sdata[255];
}

// stage 2: exclusive scan of block sums (nb <= 256), in place
__global__ __launch_bounds__(256) void scan2_kernel(int* __restrict__ bsum, int nb) {
    __shared__ int sdata[256];
    const int tid = threadIdx.x;
    int v = (tid < nb) ? bsum[tid] : 0;
    sdata[tid] = v;
    __syncthreads();
    for (int off = 1; off < 256; off <<= 1) {
        int t = 0;
        if (tid >= off) t = sdata[tid - off];
        __syncthreads();
        if (tid >= off) sdata[tid] += t;
        __syncthreads();
    }
    if (tid < nb) bsum[tid] = sdata[tid] - v;
}

// stage 3: add block offsets (no cursor needed anymore)
__global__ void scan3_kernel(int* __restrict__ row_ptr, const int* __restrict__ bsum, int n) {
    int i = blockIdx.x * blockDim.x + threadIdx.x;
    if (i >= n) return;
    row_ptr[i] += bsum[i >> 10];
}

// Atomic-free CSR fill: position precomputed in passA.
__global__ void fillB_kernel(const int* __restrict__ src, const int* __restrict__ dst,
                             const unsigned short* __restrict__ pos,
                             const int* __restrict__ row_ptr, int* __restrict__ eidx, int E) {
    int e = blockIdx.x * blockDim.x + threadIdx.x;
    if (e >= E) return;
    eidx[row_ptr[dst[e]] + pos[e]] = src[e];
}

// H1[n][m] = bf16( (sum_k X[n][k] W1[k][m]) * dinv_out[n] )
__global__ __launch_bounds__(256) void gemm1_kernel(
    const float* __restrict__ X, const float* __restrict__ W,
    const float* __restrict__ dinv_out, unsigned short* __restrict__ H1, int N) {
    __shared__ float ws[32 * 128];
    __shared__ float xs[32 * 36];
    const int tid = threadIdx.x;
    const int m0 = tid & 15;
    const int rr = tid >> 4;
    const int rbase = blockIdx.x * 32;

    float4 a00 = {0,0,0,0}, a01 = {0,0,0,0}, a10 = {0,0,0,0}, a11 = {0,0,0,0};

    for (int kt = 0; kt < 4; ++kt) {
        const float4* W4 = (const float4*)(W + kt * 32 * 128);
        float4* ws4 = (float4*)ws;
#pragma unroll
        for (int j = 0; j < 4; ++j) ws4[tid + j * 256] = W4[tid + j * 256];
        {
            int r = tid >> 3, k4 = tid & 7;
            int row = rbase + r;
            float4 v = make_float4(0.f, 0.f, 0.f, 0.f);
            if (row < N) v = *(const float4*)(X + (size_t)row * F + kt * 32 + k4 * 4);
            int base = r * 36 + k4 * 4;
            xs[base] = v.x; xs[base + 1] = v.y; xs[base + 2] = v.z; xs[base + 3] = v.w;
        }
        __syncthreads();
#pragma unroll
        for (int kk = 0; kk < 32; ++kk) {
            float xa = xs[(rr * 2) * 36 + kk];
            float xb = xs[(rr * 2 + 1) * 36 + kk];
            float4 wA = *(const float4*)(ws + kk * 128 + m0 * 4);
            float4 wB = *(const float4*)(ws + kk * 128 + 64 + m0 * 4);
            a00.x += xa * wA.x; a00.y += xa * wA.y; a00.z += xa * wA.z; a00.w += xa * wA.w;
            a01.x += xa * wB.x; a01.y += xa * wB.y; a01.z += xa * wB.z; a01.w += xa * wB.w;
            a10.x += xb * wA.x; a10.y += xb * wA.y; a10.z += xb * wA.z; a10.w += xb * wA.w;
            a11.x += xb * wB.x; a11.y += xb * wB.y; a11.z += xb * wB.z; a11.w += xb * wB.w;
        }
        __syncthreads();
    }
    int row0 = rbase + rr * 2;
    int row1 = row0 + 1;
    if (row0 < N) {
        float s = dinv_out[row0];
        ushort4 p0, p1;
        p0.x = bf16_bits(a00.x * s); p0.y = bf16_bits(a00.y * s);
        p0.z = bf16_bits(a00.z * s); p0.w = bf16_bits(a00.w * s);
        p1.x = bf16_bits(a01.x * s); p1.y = bf16_bits(a01.y * s);
        p1.z = bf16_bits(a01.z * s); p1.w = bf16_bits(a01.w * s);
        *(ushort4*)(H1 + (size_t)row0 * F + m0 * 4) = p0;
        *(ushort4*)(H1 + (size_t)row0 * F + 64 + m0 * 4) = p1;
    }
    if (row1 < N) {
        float s = dinv_out[row1];
        ushort4 p0, p1;
        p0.x = bf16_bits(a10.x * s); p0.y = bf16_bits(a10.y * s);
        p0.z = bf16_bits(a10.z * s); p0.w = bf16_bits(a10.w * s);
        p1.x = bf16_bits(a11.x * s); p1.y = bf16_bits(a11.y * s);
        p1.z = bf16_bits(a11.z * s); p1.w = bf16_bits(a11.w * s);
        *(ushort4*)(H1 + (size_t)row1 * F + m0 * 4) = p0;
        *(ushort4*)(H1 + (size_t)row1 * F + 64 + m0 * 4) = p1;
    }
}

// AGG1[n][:] = sum_{e in CSR row n} H1[eidx[e]][:]  (H1 bf16, fp32 accumulate)
__global__ __launch_bounds__(256) void spmm_csr1_kernel(
    const unsigned short* __restrict__ H1, const int* __restrict__ row_ptr,
    const int* __restrict__ cnt, const int* __restrict__ eidx,
    float* __restrict__ AGG1, int N) {
    int node = blockIdx.x * 4 + (threadIdx.x >> 6);
    if (node >= N) return;
    const int l = threadIdx.x & 63;
    const int start = row_ptr[node];
    const int deg = cnt[node];
    const unsigned int* Hb = (const unsigned int*)H1 + l;   // + s*64 per row
    float2 a0 = {0.f,0.f}, a1 = {0.f,0.f}, a2 = {0.f,0.f}, a3 = {0.f,0.f};
    int i = 0;
    for (; i + 3 < deg; i += 4) {
        int s0 = eidx[start + i];
        int s1 = eidx[start + i + 1];
        int s2 = eidx[start + i + 2];
        int s3 = eidx[start + i + 3];
        unsigned int w0 = Hb[(size_t)s0 * 64];
        unsigned int w1 = Hb[(size_t)s1 * 64];
        unsigned int w2 = Hb[(size_t)s2 * 64];
        unsigned int w3 = Hb[(size_t)s3 * 64];
        a0.x += __uint_as_float(w0 << 16); a0.y += __uint_as_float(w0 & 0xffff0000u);
        a1.x += __uint_as_float(w1 << 16); a1.y += __uint_as_float(w1 & 0xffff0000u);
        a2.x += __uint_as_float(w2 << 16); a2.y += __uint_as_float(w2 & 0xffff0000u);
        a3.x += __uint_as_float(w3 << 16); a3.y += __uint_as_float(w3 & 0xffff0000u);
    }
    for (; i < deg; ++i) {
        int s0 = eidx[start + i];
        unsigned int w0 = Hb[(size_t)s0 * 64];
        a0.x += __uint_as_float(w0 << 16); a0.y += __uint_as_float(w0 & 0xffff0000u);
    }
    float2 o = {a0.x + a1.x + a2.x + a3.x, a0.y + a1.y + a2.y + a3.y};
    *(float2*)(AGG1 + (size_t)node * F + l * 2) = o;
}

// H2[n][m] = (sum_k relu(AGG1[n][k]*dinv_in[n] + b1[k]) * W2[k][m]) * dinv_out[n]
__global__ __launch_bounds__(256) void gemm2_kernel(
    const float* __restrict__ AGG1, const float* __restrict__ b1,
    const float* __restrict__ dinv_in, const float* __restrict__ W2,
    const float* __restrict__ dinv_out, float* __restrict__ H2, int N) {
    __shared__ float ws[F * C];
    __shared__ float xs[64 * 132];
    const int tid = threadIdx.x;
    const int rbase = blockIdx.x * 64;
    {
        float4* ws4 = (float4*)ws;
        const float4* W4 = (const float4*)W2;
#pragma unroll
        for (int j = 0; j < 4; ++j) ws4[tid + j * 256] = W4[tid + j * 256];
    }
#pragma unroll
    for (int j = 0; j < 8; ++j) {
        int i4 = tid + j * 256;
        int r = i4 >> 5, k4 = i4 & 31;
        int row = rbase + r;
        float4 v = make_float4(0.f, 0.f, 0.f, 0.f);
        float di = 0.f;
        if (row < N) {
            v = *(const float4*)(AGG1 + (size_t)row * F + k4 * 4);
            di = dinv_in[row];
        }
        float4 bb = *(const float4*)(b1 + k4 * 4);
        int base = r * 132 + k4 * 4;
        xs[base]     = fmaxf(fmaf(v.x, di, bb.x), 0.f);
        xs[base + 1] = fmaxf(fmaf(v.y, di, bb.y), 0.f);
        xs[base + 2] = fmaxf(fmaf(v.z, di, bb.z), 0.f);
        xs[base + 3] = fmaxf(fmaf(v.w, di, bb.w), 0.f);
    }
    __syncthreads();
    const int m0 = tid & 7;
    const int rr = tid >> 3;
    float4 a0 = {0,0,0,0}, a1 = {0,0,0,0};
#pragma unroll 8
    for (int k = 0; k < F; ++k) {
        float4 w = *(const float4*)(ws + k * C + m0 * 4);
        float xa = xs[(rr * 2) * 132 + k];
        float xb = xs[(rr * 2 + 1) * 132 + k];
        a0.x += xa * w.x; a0.y += xa * w.y; a0.z += xa * w.z; a0.w += xa * w.w;
        a1.x += xb * w.x; a1.y += xb * w.y; a1.z += xb * w.z; a1.w += xb * w.w;
    }
    int row0 = rbase + rr * 2;
    int row1 = row0 + 1;
    if (row0 < N) {
        float s = dinv_out[row0];
        float4 o = {a0.x * s, a0.y * s, a0.z * s, a0.w * s};
        *(float4*)(H2 + (size_t)row0 * C + m0 * 4) = o;
    }
    if (row1 < N) {
        float s = dinv_out[row1];
        float4 o = {a1.x * s, a1.y * s, a1.z * s, a1.w * s};
        *(float4*)(H2 + (size_t)row1 * C + m0 * 4) = o;
    }
}

// out[n][:] = (sum_{e in row n} H2[eidx[e]][:]) * dinv_in[n] + b2
__global__ __launch_bounds__(256) void spmm_csr2_kernel(
    const float* __restrict__ H2, const int* __restrict__ row_ptr,
    const int* __restrict__ cnt, const int* __restrict__ eidx,
    const float* __restrict__ dinv_in, const float* __restrict__ b2,
    float* __restrict__ out, int N) {
    int node = blockIdx.x * 8 + (threadIdx.x >> 5);
    if (node >= N) return;
    const int col = threadIdx.x & 31;
    const int start = row_ptr[node];
    const int deg = cnt[node];
    float acc0 = 0.f, acc1 = 0.f;
    int i = 0;
    for (; i + 1 < deg; i += 2) {
        int s0 = eidx[start + i];
        int s1 = eidx[start + i + 1];
        acc0 += H2[(size_t)s0 * C + col];
        acc1 += H2[(size_t)s1 * C + col];
    }
    if (i < deg) acc0 += H2[(size_t)eidx[start + i] * C + col];
    out[(size_t)node * C + col] = fmaf(acc0 + acc1, dinv_in[node], b2[col]);
}

extern "C" void kernel_launch(void* const* d_in, const int* in_sizes, int n_in,
                              void* d_out, int out_size, void* d_ws, size_t ws_size,
                              hipStream_t stream) {
    const float* X  = (const float*)d_in[0];
    // d_in[1] = edge_encodings: unused by the reference
    const float* W1 = (const float*)d_in[2];
    const float* b1 = (const float*)d_in[3];
    const float* W2 = (const float*)d_in[4];
    const float* b2 = (const float*)d_in[5];
    const int*   ei = (const int*)d_in[6];

    const int N = in_sizes[0] / F;   // 50000
    const int E = in_sizes[6] / 2;   // 800000
    const int* src = ei;
    const int* dst = ei + E;

    // Workspace layout (4B units); total ~44 MB.
    float* wsf      = (float*)d_ws;
    float* dinv_out = wsf;                         // PADN
    float* dinv_in  = wsf + PADN;                  // PADN
    int* cnt_in  = (int*)(wsf + 2 * PADN);         // PADN
    int* row_ptr = cnt_in + PADN;                  // PADN
    int* bsum    = row_ptr + PADN;                 // 256
    unsigned short* pos = (unsigned short*)(bsum + 256);   // E u16
    int* eidx    = (int*)(pos + E);                // E
    unsigned short* H1 = (unsigned short*)(eidx + E);      // N*F bf16
    float* AGG1  = (float*)(H1 + (size_t)N * F);   // N*F fp32
    unsigned int* partial = (unsigned int*)AGG1;   // alias: HB*PADN4 u32, dead before spmm1
    float* H2    = (float*)H1;                     // alias: H1 dead after spmm_csr1
    float* outp  = (float*)d_out;                  // N*C

    hipMemsetAsync(cnt_in, 0, (size_t)PADN * sizeof(int), stream);

    passA_kernel<<<(E + 255) / 256, 256, 0, stream>>>(dst, cnt_in, pos, E);
    hist_out_kernel<<<HB, 256, 0, stream>>>(src, partial, E);
    reduce_dinv_kernel<<<(PADN4 + 255) / 256, 256, 0, stream>>>(partial, cnt_in, dinv_out, dinv_in, PADN4);
    scan1_kernel<<<SCAN_BLOCKS, 256, 0, stream>>>(cnt_in, row_ptr, bsum);
    scan2_kernel<<<1, 256, 0, stream>>>(bsum, SCAN_BLOCKS);
    scan3_kernel<<<PADN / 256, 256, 0, stream>>>(row_ptr, bsum, PADN);
    fillB_kernel<<<(E + 255) / 256, 256, 0, stream>>>(src, dst, pos, row_ptr, eidx, E);

    gemm1_kernel<<<(N + 31) / 32, 256, 0, stream>>>(X, W1, dinv_out, H1, N);
    spmm_csr1_kernel<<<(N + 3) / 4, 256, 0, stream>>>(H1, row_ptr, cnt_in, eidx, AGG1, N);
    gemm2_kernel<<<(N + 63) / 64, 256, 0, stream>>>(AGG1, b1, dinv_in, W2, dinv_out, H2, N);
    spmm_csr2_kernel<<<(N + 7) / 8, 256, 0, stream>>>(H2, row_ptr, cnt_in, eidx, dinv_in, b2, outp, N);
}

// Round 8
// 279.383 us; speedup vs baseline: 1.4308x; 1.0295x over previous
//
#include <hip/hip_runtime.h>

// GCN 2-layer, CSR aggregation. H1 bf16 via MFMA GEMM1 (bf16 in, fp32 acc).
// CSR build: passA (dst atomic count -> edge position), hist_out (LDS u8
// histogram), scan, fillB (atomic-free scatter).
// N=50000 nodes, E=800000 edges, F=128, C=32.

#define F 128
#define C 32
#define PADN 50176       // 50000 padded to 49*1024
#define SCAN_BLOCKS 49   // PADN / 1024
#define HB 256           // histogram blocks
#define PADN4 (PADN / 4) // u32 groups of 4 packed u8 counters

using bf16x8 = __attribute__((ext_vector_type(8))) short;   // 8 bf16 = 4 VGPR
using f32x4  = __attribute__((ext_vector_type(4))) float;

static __device__ __forceinline__ unsigned short bf16_bits(float f) {
    union { float f; unsigned int u; } v; v.f = f;
    unsigned int r = v.u + 0x7fffu + ((v.u >> 16) & 1u);   // round-to-nearest-even
    return (unsigned short)(r >> 16);
}

// In-degree count; atomic return value doubles as the edge's slot in its CSR row.
__global__ void passA_kernel(const int* __restrict__ dst, int* __restrict__ cnt_in,
                             unsigned short* __restrict__ pos, int E) {
    int e = blockIdx.x * blockDim.x + threadIdx.x;
    if (e >= E) return;
    int p = atomicAdd(&cnt_in[dst[e]], 1);
    pos[e] = (unsigned short)p;
}

// Out-degree partial histograms: block b histograms its edge slice over ALL nodes
// into packed-u8 LDS counters (no global atomics, each edge read once).
__global__ __launch_bounds__(256) void hist_out_kernel(
    const int* __restrict__ src, unsigned int* __restrict__ partial, int E) {
    __shared__ unsigned int h[PADN4];   // 50176 u8 counters, 50.2 KB
    const int tid = threadIdx.x;
    for (int j = tid; j < PADN4; j += 256) h[j] = 0u;
    __syncthreads();
    const int per = (E + HB - 1) / HB;
    const int lo = blockIdx.x * per;
    const int hi = min(E, lo + per);
    for (int e = lo + tid; e < hi; e += 256) {
        int v = src[e];
        atomicAdd(&h[v >> 2], 1u << ((v & 3) * 8));
    }
    __syncthreads();
    unsigned int* p = partial + (size_t)blockIdx.x * PADN4;
    for (int j = tid; j < PADN4; j += 256) p[j] = h[j];
}

// Sum u8 partials -> out-degree; fused dinv_out / dinv_in.
__global__ void reduce_dinv_kernel(const unsigned int* __restrict__ partial,
                                   const int* __restrict__ cnt_in,
                                   float* __restrict__ dinv_out, float* __restrict__ dinv_in,
                                   int n4) {
    int i = blockIdx.x * blockDim.x + threadIdx.x;
    if (i >= n4) return;
    unsigned int s0 = 0, s1 = 0, s2 = 0, s3 = 0;
#pragma unroll 8
    for (int b = 0; b < HB; ++b) {
        unsigned int w = partial[(size_t)b * PADN4 + i];
        s0 += w & 0xffu; s1 += (w >> 8) & 0xffu; s2 += (w >> 16) & 0xffu; s3 += w >> 24;
    }
    int base = i * 4;
    dinv_out[base + 0] = s0 ? rsqrtf((float)s0) : 1.0f;
    dinv_out[base + 1] = s1 ? rsqrtf((float)s1) : 1.0f;
    dinv_out[base + 2] = s2 ? rsqrtf((float)s2) : 1.0f;
    dinv_out[base + 3] = s3 ? rsqrtf((float)s3) : 1.0f;
    int4 c = *(const int4*)(cnt_in + base);
    dinv_in[base + 0] = c.x > 0 ? rsqrtf((float)c.x) : 1.0f;
    dinv_in[base + 1] = c.y > 0 ? rsqrtf((float)c.y) : 1.0f;
    dinv_in[base + 2] = c.z > 0 ? rsqrtf((float)c.z) : 1.0f;
    dinv_in[base + 3] = c.w > 0 ? rsqrtf((float)c.w) : 1.0f;
}

// exclusive scan stage 1
__global__ __launch_bounds__(256) void scan1_kernel(const int* __restrict__ cnt,
                                                    int* __restrict__ part, int* __restrict__ bsum) {
    __shared__ int sdata[256];
    const int tid = threadIdx.x;
    const int base = blockIdx.x * 1024 + tid * 4;
    int4 c = *(const int4*)(cnt + base);
    int s = c.x + c.y + c.z + c.w;
    sdata[tid] = s;
    __syncthreads();
    for (int off = 1; off < 256; off <<= 1) {
        int v = 0;
        if (tid >= off) v = sdata[tid - off];
        __syncthreads();
        if (tid >= off) sdata[tid] += v;
        __syncthreads();
    }
    int excl = sdata[tid] - s;
    part[base]     = excl;
    part[base + 1] = excl + c.x;
    part[base + 2] = excl + c.x + c.y;
    part[base + 3] = excl + c.x + c.y + c.z;
    if (tid == 255) bsum[blockIdx.x] = sdata[255];
}

// stage 2
__global__ __launch_bounds__(256) void scan2_kernel(int* __restrict__ bsum, int nb) {
    __shared__ int sdata[256];
    const int tid = threadIdx.x;
    int v = (tid < nb) ? bsum[tid] : 0;
    sdata[tid] = v;
    __syncthreads();
    for (int off = 1; off < 256; off <<= 1) {
        int t = 0;
        if (tid >= off) t = sdata[tid - off];
        __syncthreads();
        if (tid >= off) sdata[tid] += t;
        __syncthreads();
    }
    if (tid < nb) bsum[tid] = sdata[tid] - v;
}

// stage 3
__global__ void scan3_kernel(int* __restrict__ row_ptr, const int* __restrict__ bsum, int n) {
    int i = blockIdx.x * blockDim.x + threadIdx.x;
    if (i >= n) return;
    row_ptr[i] += bsum[i >> 10];
}

// Atomic-free CSR fill: position precomputed in passA.
__global__ void fillB_kernel(const int* __restrict__ src, const int* __restrict__ dst,
                             const unsigned short* __restrict__ pos,
                             const int* __restrict__ row_ptr, int* __restrict__ eidx, int E) {
    int e = blockIdx.x * blockDim.x + threadIdx.x;
    if (e >= E) return;
    eidx[row_ptr[dst[e]] + pos[e]] = src[e];
}

// H1[n][m] = bf16( (X@W1)[n][m] * dinv_out[n] ) via 16x16x32 bf16 MFMA.
// Block: 4 waves x 16 rows = 64 rows, all 128 cols. W1^T staged bf16 in LDS.
// A frag: lane l -> row l&15, k = kk*32 + (l>>4)*8 + j (j=0..7)
// B frag: lane l -> col l&15, same k chunk (reads W1T[col][k0..k0+7] contiguous)
// C/D:    lane l, reg j -> col=l&15, row=(l>>4)*4+j   [m89-verified]
__global__ __launch_bounds__(256) void gemm1_mfma_kernel(
    const float* __restrict__ X, const float* __restrict__ W,
    const float* __restrict__ dinv_out, unsigned short* __restrict__ H1, int N) {
    __shared__ unsigned short w1t[128 * 136];   // [n][k] bf16, padded stride 136
    const int tid = threadIdx.x;
    // Stage W1^T: pass p covers rows k = p*8 + (tid>>5); cols 4*(tid&31)..+3
#pragma unroll
    for (int p = 0; p < 16; ++p) {
        int k = p * 8 + (tid >> 5);
        int c4 = (tid & 31) * 4;
        float4 v = *(const float4*)(W + k * 128 + c4);
        w1t[(c4 + 0) * 136 + k] = bf16_bits(v.x);
        w1t[(c4 + 1) * 136 + k] = bf16_bits(v.y);
        w1t[(c4 + 2) * 136 + k] = bf16_bits(v.z);
        w1t[(c4 + 3) * 136 + k] = bf16_bits(v.w);
    }
    __syncthreads();

    const int lane = tid & 63;
    const int wave = tid >> 6;
    const int row0 = blockIdx.x * 64 + wave * 16;
    const int arow = row0 + (lane & 15);
    const int asrc = (arow < N) ? arow : 0;
    const int kg = (lane >> 4) * 8;   // k-chunk base within K-step

    f32x4 acc[8];
#pragma unroll
    for (int n = 0; n < 8; ++n) acc[n] = (f32x4){0.f, 0.f, 0.f, 0.f};

#pragma unroll
    for (int kk = 0; kk < 4; ++kk) {
        const float* xp = X + (size_t)asrc * F + kk * 32 + kg;
        float4 xa = *(const float4*)(xp);
        float4 xb = *(const float4*)(xp + 4);
        bf16x8 a;
        a[0] = (short)bf16_bits(xa.x); a[1] = (short)bf16_bits(xa.y);
        a[2] = (short)bf16_bits(xa.z); a[3] = (short)bf16_bits(xa.w);
        a[4] = (short)bf16_bits(xb.x); a[5] = (short)bf16_bits(xb.y);
        a[6] = (short)bf16_bits(xb.z); a[7] = (short)bf16_bits(xb.w);
#pragma unroll
        for (int n = 0; n < 8; ++n) {
            const bf16x8 b = *(const bf16x8*)(w1t + (n * 16 + (lane & 15)) * 136 + kk * 32 + kg);
            acc[n] = __builtin_amdgcn_mfma_f32_16x16x32_bf16(a, b, acc[n], 0, 0, 0);
        }
    }

    // Epilogue: scale by dinv_out[row], pack bf16, store.
    const int rbase = row0 + (lane >> 4) * 4;
#pragma unroll
    for (int j = 0; j < 4; ++j) {
        int r = rbase + j;
        if (r < N) {
            float s = dinv_out[r];
            unsigned short* out = H1 + (size_t)r * F + (lane & 15);
#pragma unroll
            for (int n = 0; n < 8; ++n) out[n * 16] = bf16_bits(acc[n][j] * s);
        }
    }
}

// AGG1[n][:] = sum_{e in CSR row n} H1[eidx[e]][:]  (H1 bf16, fp32 accumulate)
__global__ __launch_bounds__(256) void spmm_csr1_kernel(
    const unsigned short* __restrict__ H1, const int* __restrict__ row_ptr,
    const int* __restrict__ cnt, const int* __restrict__ eidx,
    float* __restrict__ AGG1, int N) {
    int node = blockIdx.x * 4 + (threadIdx.x >> 6);
    if (node >= N) return;
    const int l = threadIdx.x & 63;
    const int start = row_ptr[node];
    const int deg = cnt[node];
    const unsigned int* Hb = (const unsigned int*)H1 + l;   // + s*64 per row
    float2 a0 = {0.f,0.f}, a1 = {0.f,0.f}, a2 = {0.f,0.f}, a3 = {0.f,0.f};
    int i = 0;
    for (; i + 3 < deg; i += 4) {
        int s0 = eidx[start + i];
        int s1 = eidx[start + i + 1];
        int s2 = eidx[start + i + 2];
        int s3 = eidx[start + i + 3];
        unsigned int w0 = Hb[(size_t)s0 * 64];
        unsigned int w1 = Hb[(size_t)s1 * 64];
        unsigned int w2 = Hb[(size_t)s2 * 64];
        unsigned int w3 = Hb[(size_t)s3 * 64];
        a0.x += __uint_as_float(w0 << 16); a0.y += __uint_as_float(w0 & 0xffff0000u);
        a1.x += __uint_as_float(w1 << 16); a1.y += __uint_as_float(w1 & 0xffff0000u);
        a2.x += __uint_as_float(w2 << 16); a2.y += __uint_as_float(w2 & 0xffff0000u);
        a3.x += __uint_as_float(w3 << 16); a3.y += __uint_as_float(w3 & 0xffff0000u);
    }
    for (; i < deg; ++i) {
        int s0 = eidx[start + i];
        unsigned int w0 = Hb[(size_t)s0 * 64];
        a0.x += __uint_as_float(w0 << 16); a0.y += __uint_as_float(w0 & 0xffff0000u);
    }
    float2 o = {a0.x + a1.x + a2.x + a3.x, a0.y + a1.y + a2.y + a3.y};
    *(float2*)(AGG1 + (size_t)node * F + l * 2) = o;
}

// H2[n][m] = (sum_k relu(AGG1[n][k]*dinv_in[n] + b1[k]) * W2[k][m]) * dinv_out[n]
__global__ __launch_bounds__(256) void gemm2_kernel(
    const float* __restrict__ AGG1, const float* __restrict__ b1,
    const float* __restrict__ dinv_in, const float* __restrict__ W2,
    const float* __restrict__ dinv_out, float* __restrict__ H2, int N) {
    __shared__ float ws[F * C];
    __shared__ float xs[64 * 132];
    const int tid = threadIdx.x;
    const int rbase = blockIdx.x * 64;
    {
        float4* ws4 = (float4*)ws;
        const float4* W4 = (const float4*)W2;
#pragma unroll
        for (int j = 0; j < 4; ++j) ws4[tid + j * 256] = W4[tid + j * 256];
    }
#pragma unroll
    for (int j = 0; j < 8; ++j) {
        int i4 = tid + j * 256;
        int r = i4 >> 5, k4 = i4 & 31;
        int row = rbase + r;
        float4 v = make_float4(0.f, 0.f, 0.f, 0.f);
        float di = 0.f;
        if (row < N) {
            v = *(const float4*)(AGG1 + (size_t)row * F + k4 * 4);
            di = dinv_in[row];
        }
        float4 bb = *(const float4*)(b1 + k4 * 4);
        int base = r * 132 + k4 * 4;
        xs[base]     = fmaxf(fmaf(v.x, di, bb.x), 0.f);
        xs[base + 1] = fmaxf(fmaf(v.y, di, bb.y), 0.f);
        xs[base + 2] = fmaxf(fmaf(v.z, di, bb.z), 0.f);
        xs[base + 3] = fmaxf(fmaf(v.w, di, bb.w), 0.f);
    }
    __syncthreads();
    const int m0 = tid & 7;
    const int rr = tid >> 3;
    float4 a0 = {0,0,0,0}, a1 = {0,0,0,0};
#pragma unroll 8
    for (int k = 0; k < F; ++k) {
        float4 w = *(const float4*)(ws + k * C + m0 * 4);
        float xa = xs[(rr * 2) * 132 + k];
        float xb = xs[(rr * 2 + 1) * 132 + k];
        a0.x += xa * w.x; a0.y += xa * w.y; a0.z += xa * w.z; a0.w += xa * w.w;
        a1.x += xb * w.x; a1.y += xb * w.y; a1.z += xb * w.z; a1.w += xb * w.w;
    }
    int row0 = rbase + rr * 2;
    int row1 = row0 + 1;
    if (row0 < N) {
        float s = dinv_out[row0];
        float4 o = {a0.x * s, a0.y * s, a0.z * s, a0.w * s};
        *(float4*)(H2 + (size_t)row0 * C + m0 * 4) = o;
    }
    if (row1 < N) {
        float s = dinv_out[row1];
        float4 o = {a1.x * s, a1.y * s, a1.z * s, a1.w * s};
        *(float4*)(H2 + (size_t)row1 * C + m0 * 4) = o;
    }
}

// out[n][:] = (sum_{e in row n} H2[eidx[e]][:]) * dinv_in[n] + b2
__global__ __launch_bounds__(256) void spmm_csr2_kernel(
    const float* __restrict__ H2, const int* __restrict__ row_ptr,
    const int* __restrict__ cnt, const int* __restrict__ eidx,
    const float* __restrict__ dinv_in, const float* __restrict__ b2,
    float* __restrict__ out, int N) {
    int node = blockIdx.x * 8 + (threadIdx.x >> 5);
    if (node >= N) return;
    const int col = threadIdx.x & 31;
    const int start = row_ptr[node];
    const int deg = cnt[node];
    float acc0 = 0.f, acc1 = 0.f;
    int i = 0;
    for (; i + 1 < deg; i += 2) {
        int s0 = eidx[start + i];
        int s1 = eidx[start + i + 1];
        acc0 += H2[(size_t)s0 * C + col];
        acc1 += H2[(size_t)s1 * C + col];
    }
    if (i < deg) acc0 += H2[(size_t)eidx[start + i] * C + col];
    out[(size_t)node * C + col] = fmaf(acc0 + acc1, dinv_in[node], b2[col]);
}

extern "C" void kernel_launch(void* const* d_in, const int* in_sizes, int n_in,
                              void* d_out, int out_size, void* d_ws, size_t ws_size,
                              hipStream_t stream) {
    const float* X  = (const float*)d_in[0];
    // d_in[1] = edge_encodings: unused by the reference
    const float* W1 = (const float*)d_in[2];
    const float* b1 = (const float*)d_in[3];
    const float* W2 = (const float*)d_in[4];
    const float* b2 = (const float*)d_in[5];
    const int*   ei = (const int*)d_in[6];

    const int N = in_sizes[0] / F;   // 50000
    const int E = in_sizes[6] / 2;   // 800000
    const int* src = ei;
    const int* dst = ei + E;

    // Workspace layout (4B units); total ~44 MB.
    float* wsf      = (float*)d_ws;
    float* dinv_out = wsf;                         // PADN
    float* dinv_in  = wsf + PADN;                  // PADN
    int* cnt_in  = (int*)(wsf + 2 * PADN);         // PADN
    int* row_ptr = cnt_in + PADN;                  // PADN
    int* bsum    = row_ptr + PADN;                 // 256
    unsigned short* pos = (unsigned short*)(bsum + 256);   // E u16
    int* eidx    = (int*)(pos + E);                // E
    unsigned short* H1 = (unsigned short*)(eidx + E);      // N*F bf16
    float* AGG1  = (float*)(H1 + (size_t)N * F);   // N*F fp32
    unsigned int* partial = (unsigned int*)AGG1;   // alias: HB*PADN4 u32, dead before spmm1
    float* H2    = (float*)H1;                     // alias: H1 dead after spmm_csr1
    float* outp  = (float*)d_out;                  // N*C

    hipMemsetAsync(cnt_in, 0, (size_t)PADN * sizeof(int), stream);

    passA_kernel<<<(E + 255) / 256, 256, 0, stream>>>(dst, cnt_in, pos, E);
    hist_out_kernel<<<HB, 256, 0, stream>>>(src, partial, E);
    reduce_dinv_kernel<<<(PADN4 + 255) / 256, 256, 0, stream>>>(partial, cnt_in, dinv_out, dinv_in, PADN4);
    scan1_kernel<<<SCAN_BLOCKS, 256, 0, stream>>>(cnt_in, row_ptr, bsum);
    scan2_kernel<<<1, 256, 0, stream>>>(bsum, SCAN_BLOCKS);
    scan3_kernel<<<PADN / 256, 256, 0, stream>>>(row_ptr, bsum, PADN);
    fillB_kernel<<<(E + 255) / 256, 256, 0, stream>>>(src, dst, pos, row_ptr, eidx, E);

    gemm1_mfma_kernel<<<(N + 63) / 64, 256, 0, stream>>>(X, W1, dinv_out, H1, N);
    spmm_csr1_kernel<<<(N + 3) / 4, 256, 0, stream>>>(H1, row_ptr, cnt_in, eidx, AGG1, N);
    gemm2_kernel<<<(N + 63) / 64, 256, 0, stream>>>(AGG1, b1, dinv_in, W2, dinv_out, H2, N);
    spmm_csr2_kernel<<<(N + 7) / 8, 256, 0, stream>>>(H2, row_ptr, cnt_in, eidx, dinv_in, b2, outp, N);
}

// Round 9
// 263.287 us; speedup vs baseline: 1.5183x; 1.0611x over previous
//
#include <hip/hip_runtime.h>

// GCN 2-layer, CSR aggregation. H1/H2 bf16, fp32 accumulate; MFMA GEMM1.
// CSR build: passAB (dst atomic count->pos, src LDS hist in atomic shadow),
// reduce_scan (dinv + scan1), scan2, scan3, fillB (atomic-free scatter).
// N=50000 nodes, E=800000 edges, F=128, C=32.

#define F 128
#define C 32
#define PADN 50176       // 50000 padded to 49*1024
#define SCAN_BLOCKS 49   // PADN / 1024
#define HB 256           // edge slices / histogram blocks
#define PADN4 (PADN / 4) // u32 groups of 4 packed u8 counters

using bf16x8 = __attribute__((ext_vector_type(8))) short;   // 8 bf16 = 4 VGPR
using f32x4  = __attribute__((ext_vector_type(4))) float;

static __device__ __forceinline__ unsigned short bf16_bits(float f) {
    union { float f; unsigned int u; } v; v.f = f;
    unsigned int r = v.u + 0x7fffu + ((v.u >> 16) & 1u);   // round-to-nearest-even
    return (unsigned short)(r >> 16);
}

// Fused: in-degree atomic count (returns edge slot) + src LDS histogram.
// The LDS histogram work executes in the shadow of the memory-side atomics.
__global__ __launch_bounds__(256) void passAB_kernel(
    const int* __restrict__ src, const int* __restrict__ dst,
    int* __restrict__ cnt_in, unsigned short* __restrict__ pos,
    unsigned int* __restrict__ partial, int E) {
    __shared__ unsigned int h[PADN4];   // 50176 u8 counters, 50.2 KB
    const int tid = threadIdx.x;
    for (int j = tid; j < PADN4; j += 256) h[j] = 0u;
    __syncthreads();
    const int per = (E + HB - 1) / HB;
    const int lo = blockIdx.x * per;
    const int hi = min(E, lo + per);
    for (int e = lo + tid; e < hi; e += 256) {
        int d = dst[e];
        int p = atomicAdd(&cnt_in[d], 1);
        pos[e] = (unsigned short)p;
        int v = src[e];
        atomicAdd(&h[v >> 2], 1u << ((v & 3) * 8));
    }
    __syncthreads();
    unsigned int* p = partial + (size_t)blockIdx.x * PADN4;
    for (int j = tid; j < PADN4; j += 256) p[j] = h[j];
}

// Fused: out-degree partial reduce -> dinv_out; cnt_in -> dinv_in; scan stage 1.
// Block = 1024 nodes (256 thr x 4). part gets block-local exclusive scan of cnt_in.
__global__ __launch_bounds__(256) void reduce_scan_kernel(
    const unsigned int* __restrict__ partial, const int* __restrict__ cnt_in,
    float* __restrict__ dinv_out, float* __restrict__ dinv_in,
    int* __restrict__ part, int* __restrict__ bsum) {
    __shared__ int sdata[256];
    const int tid = threadIdx.x;
    const int i = blockIdx.x * 256 + tid;       // u32-group (4 nodes)
    unsigned int s0 = 0, s1 = 0, s2 = 0, s3 = 0;
#pragma unroll 8
    for (int b = 0; b < HB; ++b) {
        unsigned int w = partial[(size_t)b * PADN4 + i];
        s0 += w & 0xffu; s1 += (w >> 8) & 0xffu; s2 += (w >> 16) & 0xffu; s3 += w >> 24;
    }
    const int base = i * 4;
    dinv_out[base + 0] = s0 ? rsqrtf((float)s0) : 1.0f;
    dinv_out[base + 1] = s1 ? rsqrtf((float)s1) : 1.0f;
    dinv_out[base + 2] = s2 ? rsqrtf((float)s2) : 1.0f;
    dinv_out[base + 3] = s3 ? rsqrtf((float)s3) : 1.0f;
    int4 c = *(const int4*)(cnt_in + base);
    dinv_in[base + 0] = c.x > 0 ? rsqrtf((float)c.x) : 1.0f;
    dinv_in[base + 1] = c.y > 0 ? rsqrtf((float)c.y) : 1.0f;
    dinv_in[base + 2] = c.z > 0 ? rsqrtf((float)c.z) : 1.0f;
    dinv_in[base + 3] = c.w > 0 ? rsqrtf((float)c.w) : 1.0f;
    // scan stage 1 over cnt_in
    int ssum = c.x + c.y + c.z + c.w;
    sdata[tid] = ssum;
    __syncthreads();
    for (int off = 1; off < 256; off <<= 1) {
        int v = 0;
        if (tid >= off) v = sdata[tid - off];
        __syncthreads();
        if (tid >= off) sdata[tid] += v;
        __syncthreads();
    }
    int excl = sdata[tid] - ssum;
    part[base]     = excl;
    part[base + 1] = excl + c.x;
    part[base + 2] = excl + c.x + c.y;
    part[base + 3] = excl + c.x + c.y + c.z;
    if (tid == 255) bsum[blockIdx.x] = sdata[255];
}

// stage 2: exclusive scan of block sums (nb <= 256), in place
__global__ __launch_bounds__(256) void scan2_kernel(int* __restrict__ bsum, int nb) {
    __shared__ int sdata[256];
    const int tid = threadIdx.x;
    int v = (tid < nb) ? bsum[tid] : 0;
    sdata[tid] = v;
    __syncthreads();
    for (int off = 1; off < 256; off <<= 1) {
        int t = 0;
        if (tid >= off) t = sdata[tid - off];
        __syncthreads();
        if (tid >= off) sdata[tid] += t;
        __syncthreads();
    }
    if (tid < nb) bsum[tid] = sdata[tid] - v;
}

// stage 3: add block offsets
__global__ void scan3_kernel(int* __restrict__ row_ptr, const int* __restrict__ bsum, int n) {
    int i = blockIdx.x * blockDim.x + threadIdx.x;
    if (i >= n) return;
    row_ptr[i] += bsum[i >> 10];
}

// Atomic-free CSR fill: position precomputed in passAB.
__global__ void fillB_kernel(const int* __restrict__ src, const int* __restrict__ dst,
                             const unsigned short* __restrict__ pos,
                             const int* __restrict__ row_ptr, int* __restrict__ eidx, int E) {
    int e = blockIdx.x * blockDim.x + threadIdx.x;
    if (e >= E) return;
    eidx[row_ptr[dst[e]] + pos[e]] = src[e];
}

// H1[n][m] = bf16( (X@W1)[n][m] * dinv_out[n] ) via 16x16x32 bf16 MFMA.
__global__ __launch_bounds__(256) void gemm1_mfma_kernel(
    const float* __restrict__ X, const float* __restrict__ W,
    const float* __restrict__ dinv_out, unsigned short* __restrict__ H1, int N) {
    __shared__ unsigned short w1t[128 * 136];   // [n][k] bf16, padded stride 136
    const int tid = threadIdx.x;
#pragma unroll
    for (int p = 0; p < 16; ++p) {
        int k = p * 8 + (tid >> 5);
        int c4 = (tid & 31) * 4;
        float4 v = *(const float4*)(W + k * 128 + c4);
        w1t[(c4 + 0) * 136 + k] = bf16_bits(v.x);
        w1t[(c4 + 1) * 136 + k] = bf16_bits(v.y);
        w1t[(c4 + 2) * 136 + k] = bf16_bits(v.z);
        w1t[(c4 + 3) * 136 + k] = bf16_bits(v.w);
    }
    __syncthreads();

    const int lane = tid & 63;
    const int wave = tid >> 6;
    const int row0 = blockIdx.x * 64 + wave * 16;
    const int arow = row0 + (lane & 15);
    const int asrc = (arow < N) ? arow : 0;
    const int kg = (lane >> 4) * 8;

    f32x4 acc[8];
#pragma unroll
    for (int n = 0; n < 8; ++n) acc[n] = (f32x4){0.f, 0.f, 0.f, 0.f};

#pragma unroll
    for (int kk = 0; kk < 4; ++kk) {
        const float* xp = X + (size_t)asrc * F + kk * 32 + kg;
        float4 xa = *(const float4*)(xp);
        float4 xb = *(const float4*)(xp + 4);
        bf16x8 a;
        a[0] = (short)bf16_bits(xa.x); a[1] = (short)bf16_bits(xa.y);
        a[2] = (short)bf16_bits(xa.z); a[3] = (short)bf16_bits(xa.w);
        a[4] = (short)bf16_bits(xb.x); a[5] = (short)bf16_bits(xb.y);
        a[6] = (short)bf16_bits(xb.z); a[7] = (short)bf16_bits(xb.w);
#pragma unroll
        for (int n = 0; n < 8; ++n) {
            const bf16x8 b = *(const bf16x8*)(w1t + (n * 16 + (lane & 15)) * 136 + kk * 32 + kg);
            acc[n] = __builtin_amdgcn_mfma_f32_16x16x32_bf16(a, b, acc[n], 0, 0, 0);
        }
    }

    const int rbase = row0 + (lane >> 4) * 4;
#pragma unroll
    for (int j = 0; j < 4; ++j) {
        int r = rbase + j;
        if (r < N) {
            float s = dinv_out[r];
            unsigned short* out = H1 + (size_t)r * F + (lane & 15);
#pragma unroll
            for (int n = 0; n < 8; ++n) out[n * 16] = bf16_bits(acc[n][j] * s);
        }
    }
}

// AGG1[n][:] = sum_{e in CSR row n} H1[eidx[e]][:]  (H1 bf16, fp32 accumulate)
__global__ __launch_bounds__(256) void spmm_csr1_kernel(
    const unsigned short* __restrict__ H1, const int* __restrict__ row_ptr,
    const int* __restrict__ cnt, const int* __restrict__ eidx,
    float* __restrict__ AGG1, int N) {
    int node = blockIdx.x * 4 + (threadIdx.x >> 6);
    if (node >= N) return;
    const int l = threadIdx.x & 63;
    const int start = row_ptr[node];
    const int deg = cnt[node];
    const unsigned int* Hb = (const unsigned int*)H1 + l;   // + s*64 per row
    float2 a0 = {0.f,0.f}, a1 = {0.f,0.f}, a2 = {0.f,0.f}, a3 = {0.f,0.f};
    int i = 0;
    for (; i + 3 < deg; i += 4) {
        int s0 = eidx[start + i];
        int s1 = eidx[start + i + 1];
        int s2 = eidx[start + i + 2];
        int s3 = eidx[start + i + 3];
        unsigned int w0 = Hb[(size_t)s0 * 64];
        unsigned int w1 = Hb[(size_t)s1 * 64];
        unsigned int w2 = Hb[(size_t)s2 * 64];
        unsigned int w3 = Hb[(size_t)s3 * 64];
        a0.x += __uint_as_float(w0 << 16); a0.y += __uint_as_float(w0 & 0xffff0000u);
        a1.x += __uint_as_float(w1 << 16); a1.y += __uint_as_float(w1 & 0xffff0000u);
        a2.x += __uint_as_float(w2 << 16); a2.y += __uint_as_float(w2 & 0xffff0000u);
        a3.x += __uint_as_float(w3 << 16); a3.y += __uint_as_float(w3 & 0xffff0000u);
    }
    for (; i < deg; ++i) {
        int s0 = eidx[start + i];
        unsigned int w0 = Hb[(size_t)s0 * 64];
        a0.x += __uint_as_float(w0 << 16); a0.y += __uint_as_float(w0 & 0xffff0000u);
    }
    float2 o = {a0.x + a1.x + a2.x + a3.x, a0.y + a1.y + a2.y + a3.y};
    *(float2*)(AGG1 + (size_t)node * F + l * 2) = o;
}

// H2[n][m] = bf16( (sum_k relu(AGG1[n][k]*dinv_in[n]+b1[k]) * W2[k][m]) * dinv_out[n] )
__global__ __launch_bounds__(256) void gemm2_kernel(
    const float* __restrict__ AGG1, const float* __restrict__ b1,
    const float* __restrict__ dinv_in, const float* __restrict__ W2,
    const float* __restrict__ dinv_out, unsigned short* __restrict__ H2, int N) {
    __shared__ float ws[F * C];
    __shared__ float xs[64 * 132];
    const int tid = threadIdx.x;
    const int rbase = blockIdx.x * 64;
    {
        float4* ws4 = (float4*)ws;
        const float4* W4 = (const float4*)W2;
#pragma unroll
        for (int j = 0; j < 4; ++j) ws4[tid + j * 256] = W4[tid + j * 256];
    }
#pragma unroll
    for (int j = 0; j < 8; ++j) {
        int i4 = tid + j * 256;
        int r = i4 >> 5, k4 = i4 & 31;
        int row = rbase + r;
        float4 v = make_float4(0.f, 0.f, 0.f, 0.f);
        float di = 0.f;
        if (row < N) {
            v = *(const float4*)(AGG1 + (size_t)row * F + k4 * 4);
            di = dinv_in[row];
        }
        float4 bb = *(const float4*)(b1 + k4 * 4);
        int base = r * 132 + k4 * 4;
        xs[base]     = fmaxf(fmaf(v.x, di, bb.x), 0.f);
        xs[base + 1] = fmaxf(fmaf(v.y, di, bb.y), 0.f);
        xs[base + 2] = fmaxf(fmaf(v.z, di, bb.z), 0.f);
        xs[base + 3] = fmaxf(fmaf(v.w, di, bb.w), 0.f);
    }
    __syncthreads();
    const int m0 = tid & 7;
    const int rr = tid >> 3;
    float4 a0 = {0,0,0,0}, a1 = {0,0,0,0};
#pragma unroll 8
    for (int k = 0; k < F; ++k) {
        float4 w = *(const float4*)(ws + k * C + m0 * 4);
        float xa = xs[(rr * 2) * 132 + k];
        float xb = xs[(rr * 2 + 1) * 132 + k];
        a0.x += xa * w.x; a0.y += xa * w.y; a0.z += xa * w.z; a0.w += xa * w.w;
        a1.x += xb * w.x; a1.y += xb * w.y; a1.z += xb * w.z; a1.w += xb * w.w;
    }
    int row0 = rbase + rr * 2;
    int row1 = row0 + 1;
    if (row0 < N) {
        float s = dinv_out[row0];
        ushort4 o;
        o.x = bf16_bits(a0.x * s); o.y = bf16_bits(a0.y * s);
        o.z = bf16_bits(a0.z * s); o.w = bf16_bits(a0.w * s);
        *(ushort4*)(H2 + (size_t)row0 * C + m0 * 4) = o;
    }
    if (row1 < N) {
        float s = dinv_out[row1];
        ushort4 o;
        o.x = bf16_bits(a1.x * s); o.y = bf16_bits(a1.y * s);
        o.z = bf16_bits(a1.z * s); o.w = bf16_bits(a1.w * s);
        *(ushort4*)(H2 + (size_t)row1 * C + m0 * 4) = o;
    }
}

// out[n][:] = (sum_{e in row n} H2[eidx[e]][:]) * dinv_in[n] + b2   (H2 bf16)
// 16 lanes per node, lane = col pair (u32 = 2 bf16)
__global__ __launch_bounds__(256) void spmm_csr2_kernel(
    const unsigned int* __restrict__ H2, const int* __restrict__ row_ptr,
    const int* __restrict__ cnt, const int* __restrict__ eidx,
    const float* __restrict__ dinv_in, const float* __restrict__ b2,
    float* __restrict__ out, int N) {
    int node = blockIdx.x * 16 + (threadIdx.x >> 4);
    if (node >= N) return;
    const int l = threadIdx.x & 15;
    const int start = row_ptr[node];
    const int deg = cnt[node];
    const unsigned int* Hb = H2 + l;   // + s*16 per row
    float2 a0 = {0.f, 0.f}, a1 = {0.f, 0.f};
    int i = 0;
    for (; i + 1 < deg; i += 2) {
        unsigned int w0 = Hb[(size_t)eidx[start + i] * 16];
        unsigned int w1 = Hb[(size_t)eidx[start + i + 1] * 16];
        a0.x += __uint_as_float(w0 << 16); a0.y += __uint_as_float(w0 & 0xffff0000u);
        a1.x += __uint_as_float(w1 << 16); a1.y += __uint_as_float(w1 & 0xffff0000u);
    }
    if (i < deg) {
        unsigned int w0 = Hb[(size_t)eidx[start + i] * 16];
        a0.x += __uint_as_float(w0 << 16); a0.y += __uint_as_float(w0 & 0xffff0000u);
    }
    float di = dinv_in[node];
    float2 bb = *(const float2*)(b2 + l * 2);
    float2 o = { fmaf(a0.x + a1.x, di, bb.x), fmaf(a0.y + a1.y, di, bb.y) };
    *(float2*)(out + (size_t)node * C + l * 2) = o;
}

extern "C" void kernel_launch(void* const* d_in, const int* in_sizes, int n_in,
                              void* d_out, int out_size, void* d_ws, size_t ws_size,
                              hipStream_t stream) {
    const float* X  = (const float*)d_in[0];
    // d_in[1] = edge_encodings: unused by the reference
    const float* W1 = (const float*)d_in[2];
    const float* b1 = (const float*)d_in[3];
    const float* W2 = (const float*)d_in[4];
    const float* b2 = (const float*)d_in[5];
    const int*   ei = (const int*)d_in[6];

    const int N = in_sizes[0] / F;   // 50000
    const int E = in_sizes[6] / 2;   // 800000
    const int* src = ei;
    const int* dst = ei + E;

    // Workspace layout (4B units); total ~44 MB.
    float* wsf      = (float*)d_ws;
    float* dinv_out = wsf;                         // PADN
    float* dinv_in  = wsf + PADN;                  // PADN
    int* cnt_in  = (int*)(wsf + 2 * PADN);         // PADN
    int* row_ptr = cnt_in + PADN;                  // PADN
    int* bsum    = row_ptr + PADN;                 // 256
    unsigned short* pos = (unsigned short*)(bsum + 256);   // E u16
    int* eidx    = (int*)(pos + E);                // E
    unsigned short* H1 = (unsigned short*)(eidx + E);      // N*F bf16
    float* AGG1  = (float*)(H1 + (size_t)N * F);   // N*F fp32
    unsigned int* partial = (unsigned int*)AGG1;   // alias: HB*PADN4 u32, dead before spmm1
    unsigned short* H2 = H1;                       // alias: H1 dead after spmm_csr1
    float* outp  = (float*)d_out;                  // N*C

    hipMemsetAsync(cnt_in, 0, (size_t)PADN * sizeof(int), stream);

    passAB_kernel<<<HB, 256, 0, stream>>>(src, dst, cnt_in, pos, partial, E);
    reduce_scan_kernel<<<SCAN_BLOCKS, 256, 0, stream>>>(partial, cnt_in, dinv_out, dinv_in, row_ptr, bsum);
    scan2_kernel<<<1, 256, 0, stream>>>(bsum, SCAN_BLOCKS);
    scan3_kernel<<<PADN / 256, 256, 0, stream>>>(row_ptr, bsum, PADN);
    fillB_kernel<<<(E + 255) / 256, 256, 0, stream>>>(src, dst, pos, row_ptr, eidx, E);

    gemm1_mfma_kernel<<<(N + 63) / 64, 256, 0, stream>>>(X, W1, dinv_out, H1, N);
    spmm_csr1_kernel<<<(N + 3) / 4, 256, 0, stream>>>(H1, row_ptr, cnt_in, eidx, AGG1, N);
    gemm2_kernel<<<(N + 63) / 64, 256, 0, stream>>>(AGG1, b1, dinv_in, W2, dinv_out, H2, N);
    spmm_csr2_kernel<<<(N + 15) / 16, 256, 0, stream>>>((const unsigned int*)H2, row_ptr, cnt_in, eidx, dinv_in, b2, outp, N);
}